// Round 3
// baseline (7319.518 us; speedup 1.0000x reference)
//
#include <hip/hip_runtime.h>
#include <math.h>

#define Q 2048
#define NOBS 8192
#define NSTEPS 32
#define NBLK 256

// ---------------------------------------------------------------------------
__device__ __forceinline__ float block_sum256(float v, volatile float* red) {
  int tid = threadIdx.x;
#pragma unroll
  for (int o = 32; o > 0; o >>= 1) v += __shfl_down(v, o);
  __syncthreads();
  if ((tid & 63) == 0) red[tid >> 6] = v;
  __syncthreads();
  return red[0] + red[1] + red[2] + red[3];
}

// ---------------------------------------------------------------------------
// Hand-rolled grid barrier: per-block arrival flags + single release word.
// Agent-scope fences make plain (L2-cached) data visible across XCDs.
__device__ __forceinline__ void gbar(unsigned* arrive, unsigned* release,
                                     unsigned ep) {
  __syncthreads();
  __threadfence();   // release: write back dirty L2 before signaling
  int tid = threadIdx.x;
  if (blockIdx.x == 0) {
    if (tid > 0) {
      while (__hip_atomic_load(&arrive[tid], __ATOMIC_RELAXED,
                               __HIP_MEMORY_SCOPE_AGENT) < ep) { }
    }
    __syncthreads();
    if (tid == 0)
      __hip_atomic_store(release, ep, __ATOMIC_RELAXED,
                         __HIP_MEMORY_SCOPE_AGENT);
  } else {
    if (tid == 0) {
      __hip_atomic_store(&arrive[blockIdx.x], ep, __ATOMIC_RELAXED,
                         __HIP_MEMORY_SCOPE_AGENT);
      while (__hip_atomic_load(release, __ATOMIC_RELAXED,
                               __HIP_MEMORY_SCOPE_AGENT) < ep) { }
    }
  }
  __syncthreads();
  __threadfence();   // acquire: invalidate L1/L2 before reading others' data
}

// ---------------------------------------------------------------------------
__global__ __launch_bounds__(256) void obs_kernel(
    const float* __restrict__ yt, const float* __restrict__ yp,
    const int* __restrict__ zidx, const float* __restrict__ s2e_p,
    const float* __restrict__ s2b_p, float* __restrict__ t,
    int* __restrict__ cnt, float* __restrict__ scal) {
  __shared__ float red[4];
  int i = blockIdx.x * 256 + threadIdx.x;
  float s2e = s2e_p[0], s2b = s2b_p[0];
  float sig2 = s2e + s2b;
  float r = yt[i] - yp[i];
  float e = erff(r * rsqrtf(2.0f * sig2));
  float u = 0.5f * (e + 1.0f);
  u = fminf(fmaxf(u, 1e-5f), 1.0f - 1e-5f);
  float m = erfinvf(2.0f * u - 1.0f) * 1.4142135623730951f;
  float slp = -0.5f * logf(2.0f * 3.14159265358979f * sig2) - r * r / (2.0f * sig2);
  int z = zidx[i];
  atomicAdd(&t[z], m);
  atomicAdd(&cnt[z], 1);
  float s1 = block_sum256(slp, red);
  float s2 = block_sum256(m * m, red);
  if (threadIdx.x == 0) {
    atomicAdd(&scal[0], s1);   // sum_log_pdf
    atomicAdd(&scal[1], s2);   // m'm
  }
}

// ---------------------------------------------------------------------------
__global__ __launch_bounds__(256) void build_G(
    const float* __restrict__ dist, const float* __restrict__ s2e_p,
    const float* __restrict__ s2b_p, const float* __restrict__ ell_p,
    const int* __restrict__ cnt, float* __restrict__ G) {
  int idx = blockIdx.x * 256 + threadIdx.x;
  int j = idx >> 11;
  int k = idx & (Q - 1);
  float s2e = s2e_p[0], s2b = s2b_p[0], ell = ell_p[0];
  float sig2 = s2e + s2b;
  float a = (s2b / sig2) * expf(-dist[idx] / (2.0f * ell));
  float g = sqrtf((float)cnt[j] * (float)cnt[k]) * a;
  if (j == k) g += s2e / sig2;
  G[idx] = g;
}

// ---------------------------------------------------------------------------
__global__ __launch_bounds__(256) void matvec_kernel(
    const float* __restrict__ dist, const float* __restrict__ s2e_p,
    const float* __restrict__ s2b_p, const float* __restrict__ ell_p,
    const int* __restrict__ cnt, const float* __restrict__ t,
    float* __restrict__ z, float* __restrict__ scal) {
  __shared__ float red[4];
  int j = blockIdx.x;
  float s2e = s2e_p[0], s2b = s2b_p[0], ell = ell_p[0];
  float sig2 = s2e + s2b;
  float inv2ell = 1.0f / (2.0f * ell);
  float s = 0.0f;
  const float* drow = dist + (size_t)j * Q;
  for (int k = threadIdx.x; k < Q; k += 256) s += expf(-drow[k] * inv2ell) * t[k];
  float tot = block_sum256(s, red);
  if (threadIdx.x == 0) {
    float wj = (s2b / sig2) * tot;
    z[j] = sqrtf((float)cnt[j]) * wj;   // b = W^{1/2} w
    atomicAdd(&scal[2], t[j] * wj);     // t.w
  }
}

// ---------------------------------------------------------------------------
// Wave-level 64x64 Cholesky: row per lane in registers. src row stride = Q.
__device__ __forceinline__ void wave_chol64(const float* src, float* rr) {
  int lane = threadIdx.x & 63;
  const float* row = src + (size_t)lane * Q;
#pragma unroll
  for (int k4 = 0; k4 < 16; ++k4) {
    float4 v = *(const float4*)(row + k4 * 4);
    rr[k4 * 4 + 0] = v.x; rr[k4 * 4 + 1] = v.y;
    rr[k4 * 4 + 2] = v.z; rr[k4 * 4 + 3] = v.w;
  }
#pragma unroll
  for (int j = 0; j < 64; ++j) {
    float vjj = __shfl(rr[j], j);
    float invd = rsqrtf(vjj);
    float lij = rr[j] * invd;   // lane j gets sqrt(vjj)
    rr[j] = lij;
#pragma unroll
    for (int k = 0; k < 64; ++k)
      if (k > j) rr[k] -= lij * __shfl(lij, k);
  }
}

// ---------------------------------------------------------------------------
// One 64x64 trailing-update tile: G[R0:,C0:] -= P * Qt^T (panel at col j0).
__device__ __forceinline__ void syrk_tile(float* __restrict__ G, int j0,
                                          int R0, int C0, float* shA,
                                          float* shB) {
  int tid = threadIdx.x;
  for (int it = 0; it < 4; ++it) {
    int idx = it * 256 + tid;
    int r = idx >> 4, c4 = (idx & 15) * 4;
    float4 v = *(const float4*)(G + (size_t)(R0 + r) * Q + j0 + c4);
    shA[(c4 + 0) * 68 + r] = v.x; shA[(c4 + 1) * 68 + r] = v.y;
    shA[(c4 + 2) * 68 + r] = v.z; shA[(c4 + 3) * 68 + r] = v.w;
    float4 u = *(const float4*)(G + (size_t)(C0 + r) * Q + j0 + c4);
    shB[(c4 + 0) * 68 + r] = u.x; shB[(c4 + 1) * 68 + r] = u.y;
    shB[(c4 + 2) * 68 + r] = u.z; shB[(c4 + 3) * 68 + r] = u.w;
  }
  __syncthreads();
  int tx = tid & 15, ty = tid >> 4;
  float acc[4][4] = {{0.f}};
  for (int p = 0; p < 64; ++p) {
    float4 a4 = *(const float4*)&shA[p * 68 + ty * 4];
    float4 b4 = *(const float4*)&shB[p * 68 + tx * 4];
    float av[4] = {a4.x, a4.y, a4.z, a4.w};
    float bv[4] = {b4.x, b4.y, b4.z, b4.w};
#pragma unroll
    for (int i = 0; i < 4; ++i)
#pragma unroll
      for (int jj = 0; jj < 4; ++jj) acc[i][jj] += av[i] * bv[jj];
  }
#pragma unroll
  for (int i = 0; i < 4; ++i) {
    float* gp = G + (size_t)(R0 + ty * 4 + i) * Q + C0 + tx * 4;
    float4 g = *(float4*)gp;
    g.x -= acc[i][0]; g.y -= acc[i][1];
    g.z -= acc[i][2]; g.w -= acc[i][3];
    *(float4*)gp = g;
  }
}

// ---------------------------------------------------------------------------
// Cooperative blocked Cholesky with RHS carried as virtual row; custom
// barrier; next-step diag factored by block 0 during phase C (lookahead).
__global__ __launch_bounds__(256, 1) void chol_coop(
    float* __restrict__ G, float* __restrict__ z, float* __restrict__ scal,
    unsigned* arrive, unsigned* release, float* __restrict__ ldstage,
    const float* __restrict__ s2e_p, const float* __restrict__ s2b_p,
    float* __restrict__ out) {
  __shared__ __align__(16) float shA[64 * 68];
  __shared__ __align__(16) float shB[64 * 68];
  __shared__ float z1s[64];
  __shared__ float red[256];
  int tid = threadIdx.x;
  int lane = tid & 63, wv = tid >> 6;
  int bx = blockIdx.x;
  unsigned ep = 0;

  for (int s = 0; s < NSTEPS; ++s) {
    int j0 = s * 64;
    int ntr = Q - j0 - 64;
    int nb = ntr >> 6;
    int Rtot = ntr + 1;   // trailing rows + z row

    // ---- obtain factored diag tile into shA (stride 65, lower) ----
    if (s == 0) {
      if (wv == 0) {
        float rr[64];
        wave_chol64(G, rr);
        float dv = 1.0f;
#pragma unroll
        for (int k = 0; k < 64; ++k) {
          if (k <= lane) shA[lane * 65 + k] = rr[k];
          if (k == lane) dv = rr[k];
        }
        if (bx == 0) {
          float lg = logf(dv);
#pragma unroll
          for (int o = 32; o > 0; o >>= 1) lg += __shfl_down(lg, o);
          if (lane == 0) atomicAdd(&scal[3], lg);
        }
      }
    } else {
      // staged by block 0 last step: 64x64 row-major
      for (int it = 0; it < 4; ++it) {
        int idx = it * 256 + tid;
        int r = idx >> 4, c4 = (idx & 15) * 4;
        float4 v = *(const float4*)(ldstage + r * 64 + c4);
        shA[r * 65 + c4 + 0] = v.x; shA[r * 65 + c4 + 1] = v.y;
        shA[r * 65 + c4 + 2] = v.z; shA[r * 65 + c4 + 3] = v.w;
      }
    }
    __syncthreads();

    // ---- phase B: TRSM trailing rows + z row ----
    {
      float dinv = 1.0f / shA[lane * 65 + lane];
      int gw = bx * 4 + wv;
      for (int ri = gw; ri < Rtot; ri += NBLK * 4) {
        int r = j0 + 64 + ri;
        float* grow = (r < Q) ? (G + (size_t)r * Q + j0) : (z + j0);
        float a = grow[lane];
        for (int p = 0; p < 64; ++p) {
          float xp = __shfl(a, p) * __shfl(dinv, p);
          if (lane > p) a -= xp * shA[lane * 65 + p];
        }
        grow[lane] = a * dinv;
      }
    }
    gbar(arrive, release, ++ep);

    // ---- phase C: trailing SYRK + z update; block 0 preps next diag ----
    if (nb > 0) {
      int ntri = nb * (nb + 1) / 2;
      if (bx == 0) {
        int D0 = j0 + 64;
        syrk_tile(G, j0, D0, D0, shA, shB);   // update next diag tile
        __syncthreads();
        if (wv == 0) {
          float rr[64];
          wave_chol64(G + (size_t)D0 * Q + D0, rr);
          float dv = 1.0f;
#pragma unroll
          for (int k4 = 0; k4 < 16; ++k4) {
            *(float4*)(ldstage + lane * 64 + k4 * 4) =
                make_float4(rr[k4 * 4 + 0], rr[k4 * 4 + 1],
                            rr[k4 * 4 + 2], rr[k4 * 4 + 3]);
#pragma unroll
            for (int j = 0; j < 4; ++j)
              if (k4 * 4 + j == lane) dv = rr[k4 * 4 + j];
          }
          float lg = logf(dv);
#pragma unroll
          for (int o = 32; o > 0; o >>= 1) lg += __shfl_down(lg, o);
          if (lane == 0) atomicAdd(&scal[3], lg);
        }
      } else {
        int njobs = ntri + nb;
        for (int job = bx - 1; job < njobs; job += NBLK - 1) {
          __syncthreads();
          if (job < ntri) {
            if (job == 0) continue;   // diag tile: block 0's
            int bi = (int)((sqrtf(8.0f * (float)job + 1.0f) - 1.0f) * 0.5f);
            while ((bi + 1) * (bi + 2) / 2 <= job) ++bi;
            while (bi * (bi + 1) / 2 > job) --bi;
            int bk = job - bi * (bi + 1) / 2;
            syrk_tile(G, j0, j0 + 64 + bi * 64, j0 + 64 + bk * 64, shA, shB);
          } else {
            int bk = job - ntri;
            int C0 = j0 + 64 + bk * 64;
            if (tid < 64) z1s[tid] = z[j0 + tid];
            __syncthreads();
            int rw = tid >> 2, part = tid & 3;
            const float* Lr = G + (size_t)(C0 + rw) * Q + j0;
            float ssum = 0.f;
            for (int p = part; p < 64; p += 4) ssum += Lr[p] * z1s[p];
            ssum += __shfl_down(ssum, 2);
            ssum += __shfl_down(ssum, 1);
            if (part == 0) z[C0 + rw] -= ssum;
          }
        }
      }
    }
    gbar(arrive, release, ++ep);
  }

  // ---- final assembly (block 0) ----
  if (bx == 0) {
    float bv = 0.f;
    for (int i = tid; i < Q; i += 256) { float zi = z[i]; bv += zi * zi; }
    float bvs = block_sum256(bv, red);
    if (tid == 0) {
      float s2e = s2e_p[0], s2b = s2b_p[0];
      float sig2 = s2e + s2b;
      float c = s2e / sig2;
      float slp = scal[0], mtm = scal[1], tw = scal[2], sl = scal[3];
      float tty = (tw - bvs) / c;          // t' y
      float mrm = (mtm - tty) / c;         // m' R^{-1} m
      float logdetR = (float)(NOBS - Q) * logf(c) + 2.0f * sl;
      out[0] = 0.5f * logdetR + 0.5f * mrm - 0.5f * mtm + 0.5f * slp;
    }
  }
}

// ---------------------------------------------------------------------------
extern "C" void kernel_launch(void* const* d_in, const int* in_sizes, int n_in,
                              void* d_out, int out_size, void* d_ws, size_t ws_size,
                              hipStream_t stream) {
  const float* yt   = (const float*)d_in[0];
  const float* yp   = (const float*)d_in[1];
  const int*   zidx = (const int*)d_in[2];
  const float* dist = (const float*)d_in[3];
  const float* s2e  = (const float*)d_in[4];
  const float* s2b  = (const float*)d_in[5];
  const float* ell  = (const float*)d_in[6];

  float* ws   = (float*)d_ws;
  float* G    = ws;                         // Q*Q floats = 16 MB
  float* z    = ws + (size_t)Q * Q;         // Q
  float* t    = z + Q;                      // Q
  int*   cnt  = (int*)(t + Q);              // Q ints
  float* scal = t + 2 * Q;                  // 8: slp, mtm, tw, sumlogL
  unsigned* arrive  = (unsigned*)(scal + 8);   // 256
  unsigned* release = arrive + 256;            // 1 (+3 pad)
  float* ldstage = (float*)(release + 4);      // 64*64 staged diag factor

  // zero t, cnt, scal, barrier flags
  hipMemsetAsync(t, 0, (2 * Q + 8 + 260) * sizeof(float), stream);

  obs_kernel<<<NOBS / 256, 256, 0, stream>>>(yt, yp, zidx, s2e, s2b, t, cnt, scal);
  build_G<<<(Q * Q) / 256, 256, 0, stream>>>(dist, s2e, s2b, ell, cnt, G);
  matvec_kernel<<<Q, 256, 0, stream>>>(dist, s2e, s2b, ell, cnt, t, z, scal);

  float* outp = (float*)d_out;
  void* args[] = {&G, &z, &scal, &arrive, &release, &ldstage,
                  (void*)&s2e, (void*)&s2b, &outp};
  hipLaunchCooperativeKernel((const void*)chol_coop, dim3(NBLK), dim3(256),
                             args, 0, stream);
}

// Round 5
// 6886.378 us; speedup vs baseline: 1.0629x; 1.0629x over previous
//
#include <hip/hip_runtime.h>
#include <math.h>

#define Q 2048
#define NOBS 8192
#define NSTEPS 32
#define NBLK 256

// ---------------------------------------------------------------------------
// Agent-scope coherent (IF-level) accessors: bypass L1/L2 (sc0 sc1), so no
// cache-maintenance fences are ever needed for cross-XCD visibility.
__device__ __forceinline__ float2 coh_load8(const float* p) {
  unsigned long long v = __hip_atomic_load((const unsigned long long*)p,
      __ATOMIC_RELAXED, __HIP_MEMORY_SCOPE_AGENT);
  float2 r;
  r.x = __uint_as_float((unsigned)(v & 0xffffffffull));
  r.y = __uint_as_float((unsigned)(v >> 32));
  return r;
}
__device__ __forceinline__ void coh_store8(float* p, float a, float b) {
  unsigned long long v = ((unsigned long long)__float_as_uint(b) << 32) |
                         (unsigned long long)__float_as_uint(a);
  __hip_atomic_store((unsigned long long*)p, v, __ATOMIC_RELAXED,
                     __HIP_MEMORY_SCOPE_AGENT);
}
__device__ __forceinline__ float coh_load4(const float* p) {
  unsigned v = __hip_atomic_load((const unsigned*)p, __ATOMIC_RELAXED,
                                 __HIP_MEMORY_SCOPE_AGENT);
  return __uint_as_float(v);
}
__device__ __forceinline__ void coh_store4(float* p, float x) {
  __hip_atomic_store((unsigned*)p, __float_as_uint(x), __ATOMIC_RELAXED,
                     __HIP_MEMORY_SCOPE_AGENT);
}

// ---------------------------------------------------------------------------
__device__ __forceinline__ float block_sum256(float v, volatile float* red) {
  int tid = threadIdx.x;
#pragma unroll
  for (int o = 32; o > 0; o >>= 1) v += __shfl_down(v, o);
  __syncthreads();
  if ((tid & 63) == 0) red[tid >> 6] = v;
  __syncthreads();
  return red[0] + red[1] + red[2] + red[3];
}

// ---------------------------------------------------------------------------
// Fence-free grid barrier: all shared data moves via sc1 ops, so we only
// drain our own stores (vmcnt) and do an IF-atomic flag rendezvous.
// Requires all NBLK blocks co-resident (grid == 256 == #CUs, 36KB LDS).
__device__ __forceinline__ void gbar(unsigned* arrive, unsigned* release,
                                     unsigned ep) {
  __syncthreads();
  asm volatile("s_waitcnt vmcnt(0)" ::: "memory");
  int tid = threadIdx.x;
  if (blockIdx.x == 0) {
    if (tid > 0) {
      while (__hip_atomic_load(&arrive[tid], __ATOMIC_RELAXED,
                               __HIP_MEMORY_SCOPE_AGENT) < ep) { }
    }
    __syncthreads();
    if (tid == 0)
      __hip_atomic_store(release, ep, __ATOMIC_RELAXED,
                         __HIP_MEMORY_SCOPE_AGENT);
  } else {
    if (tid == 0) {
      __hip_atomic_store(&arrive[blockIdx.x], ep, __ATOMIC_RELAXED,
                         __HIP_MEMORY_SCOPE_AGENT);
      while (__hip_atomic_load(release, __ATOMIC_RELAXED,
                               __HIP_MEMORY_SCOPE_AGENT) < ep) { }
    }
  }
  __syncthreads();
}

// ---------------------------------------------------------------------------
__global__ __launch_bounds__(256) void obs_kernel(
    const float* __restrict__ yt, const float* __restrict__ yp,
    const int* __restrict__ zidx, const float* __restrict__ s2e_p,
    const float* __restrict__ s2b_p, float* __restrict__ t,
    int* __restrict__ cnt, float* __restrict__ scal) {
  __shared__ float red[4];
  int i = blockIdx.x * 256 + threadIdx.x;
  float s2e = s2e_p[0], s2b = s2b_p[0];
  float sig2 = s2e + s2b;
  float r = yt[i] - yp[i];
  float e = erff(r * rsqrtf(2.0f * sig2));
  float u = 0.5f * (e + 1.0f);
  u = fminf(fmaxf(u, 1e-5f), 1.0f - 1e-5f);
  float m = erfinvf(2.0f * u - 1.0f) * 1.4142135623730951f;
  float slp = -0.5f * logf(2.0f * 3.14159265358979f * sig2) - r * r / (2.0f * sig2);
  int z = zidx[i];
  atomicAdd(&t[z], m);
  atomicAdd(&cnt[z], 1);
  float s1 = block_sum256(slp, red);
  float s2 = block_sum256(m * m, red);
  if (threadIdx.x == 0) {
    atomicAdd(&scal[0], s1);   // sum_log_pdf
    atomicAdd(&scal[1], s2);   // m'm
  }
}

// ---------------------------------------------------------------------------
__global__ __launch_bounds__(256) void build_G(
    const float* __restrict__ dist, const float* __restrict__ s2e_p,
    const float* __restrict__ s2b_p, const float* __restrict__ ell_p,
    const int* __restrict__ cnt, float* __restrict__ G) {
  int idx = blockIdx.x * 256 + threadIdx.x;
  int j = idx >> 11;
  int k = idx & (Q - 1);
  float s2e = s2e_p[0], s2b = s2b_p[0], ell = ell_p[0];
  float sig2 = s2e + s2b;
  float a = (s2b / sig2) * expf(-dist[idx] / (2.0f * ell));
  float g = sqrtf((float)cnt[j] * (float)cnt[k]) * a;
  if (j == k) g += s2e / sig2;
  G[idx] = g;
}

// ---------------------------------------------------------------------------
__global__ __launch_bounds__(256) void matvec_kernel(
    const float* __restrict__ dist, const float* __restrict__ s2e_p,
    const float* __restrict__ s2b_p, const float* __restrict__ ell_p,
    const int* __restrict__ cnt, const float* __restrict__ t,
    float* __restrict__ z, float* __restrict__ scal) {
  __shared__ float red[4];
  int j = blockIdx.x;
  float s2e = s2e_p[0], s2b = s2b_p[0], ell = ell_p[0];
  float sig2 = s2e + s2b;
  float inv2ell = 1.0f / (2.0f * ell);
  float s = 0.0f;
  const float* drow = dist + (size_t)j * Q;
  for (int k = threadIdx.x; k < Q; k += 256) s += expf(-drow[k] * inv2ell) * t[k];
  float tot = block_sum256(s, red);
  if (threadIdx.x == 0) {
    float wj = (s2b / sig2) * tot;
    z[j] = sqrtf((float)cnt[j]) * wj;   // b = W^{1/2} w
    atomicAdd(&scal[2], t[j] * wj);     // t.w
  }
}

// ---------------------------------------------------------------------------
// Wave-level 64x64 Cholesky, rows in registers; coherent loads, stride Q.
__device__ __forceinline__ void wave_chol64_coh(const float* src, float* rr) {
  int lane = threadIdx.x & 63;
  const float* row = src + (size_t)lane * Q;
#pragma unroll
  for (int k2 = 0; k2 < 32; ++k2) {
    float2 v = coh_load8(row + k2 * 2);
    rr[k2 * 2 + 0] = v.x; rr[k2 * 2 + 1] = v.y;
  }
#pragma unroll
  for (int j = 0; j < 64; ++j) {
    float vjj = __shfl(rr[j], j);
    float invd = rsqrtf(vjj);
    float lij = rr[j] * invd;   // lane j gets sqrt(vjj)
    rr[j] = lij;
#pragma unroll
    for (int k = 0; k < 64; ++k)
      if (k > j) rr[k] -= lij * __shfl(lij, k);
  }
}

// ---------------------------------------------------------------------------
// One 64x64 trailing-update tile: G[R0:,C0:] -= P * Qt^T (panel at col j0).
__device__ __forceinline__ void syrk_tile(float* __restrict__ G, int j0,
                                          int R0, int C0, float* shA,
                                          float* shB) {
  int tid = threadIdx.x;
  for (int it = 0; it < 8; ++it) {
    int idx = it * 256 + tid;           // 2048 8B chunks
    int r = idx >> 5, c2 = (idx & 31) * 2;
    float2 v = coh_load8(G + (size_t)(R0 + r) * Q + j0 + c2);
    shA[(c2 + 0) * 68 + r] = v.x; shA[(c2 + 1) * 68 + r] = v.y;
    float2 u = coh_load8(G + (size_t)(C0 + r) * Q + j0 + c2);
    shB[(c2 + 0) * 68 + r] = u.x; shB[(c2 + 1) * 68 + r] = u.y;
  }
  __syncthreads();
  int tx = tid & 15, ty = tid >> 4;
  float acc[4][4] = {{0.f}};
  for (int p = 0; p < 64; ++p) {
    float4 a4 = *(const float4*)&shA[p * 68 + ty * 4];
    float4 b4 = *(const float4*)&shB[p * 68 + tx * 4];
    float av[4] = {a4.x, a4.y, a4.z, a4.w};
    float bv[4] = {b4.x, b4.y, b4.z, b4.w};
#pragma unroll
    for (int i = 0; i < 4; ++i)
#pragma unroll
      for (int jj = 0; jj < 4; ++jj) acc[i][jj] += av[i] * bv[jj];
  }
#pragma unroll
  for (int i = 0; i < 4; ++i) {
    float* gp = G + (size_t)(R0 + ty * 4 + i) * Q + C0 + tx * 4;
    float2 g0 = coh_load8(gp);
    float2 g1 = coh_load8(gp + 2);
    coh_store8(gp,     g0.x - acc[i][0], g0.y - acc[i][1]);
    coh_store8(gp + 2, g1.x - acc[i][2], g1.y - acc[i][3]);
  }
}

// ---------------------------------------------------------------------------
// Blocked Cholesky with RHS carried as a virtual row; fence-free custom
// barrier; next-step diag factored by block 0 during phase C (lookahead).
// Plain launch: grid == NBLK == 256 == #CUs guarantees co-residency.
__global__ __launch_bounds__(256, 1) void chol_coop(
    float* __restrict__ G, float* __restrict__ z, float* __restrict__ scal,
    unsigned* arrive, unsigned* release, float* __restrict__ ldstage,
    const float* __restrict__ s2e_p, const float* __restrict__ s2b_p,
    float* __restrict__ out) {
  __shared__ __align__(16) float shA[64 * 68];
  __shared__ __align__(16) float shB[64 * 68];
  __shared__ float z1s[64];
  __shared__ float red[256];
  int tid = threadIdx.x;
  int lane = tid & 63, wv = tid >> 6;
  int bx = blockIdx.x;
  unsigned ep = 0;

  for (int s = 0; s < NSTEPS; ++s) {
    int j0 = s * 64;
    int ntr = Q - j0 - 64;
    int nb = ntr >> 6;
    int Rtot = ntr + 1;   // trailing rows + z row

    // ---- obtain factored diag tile into shA (stride 65, lower) ----
    if (s == 0) {
      if (wv == 0) {
        float rr[64];
        wave_chol64_coh(G, rr);
        float dv = 1.0f;
#pragma unroll
        for (int k = 0; k < 64; ++k) {
          if (k <= lane) shA[lane * 65 + k] = rr[k];
          if (k == lane) dv = rr[k];
        }
        if (bx == 0) {
          float lg = logf(dv);
#pragma unroll
          for (int o = 32; o > 0; o >>= 1) lg += __shfl_down(lg, o);
          if (lane == 0) atomicAdd(&scal[3], lg);
        }
      }
    } else {
      for (int it = 0; it < 2; ++it) {
        int idx = it * 256 + tid;        // 512 8B chunks
        int r = idx >> 3, c2 = (idx & 7) * 8;
        float2 v0 = coh_load8(ldstage + r * 64 + c2);
        float2 v1 = coh_load8(ldstage + r * 64 + c2 + 2);
        float2 v2 = coh_load8(ldstage + r * 64 + c2 + 4);
        float2 v3 = coh_load8(ldstage + r * 64 + c2 + 6);
        shA[r * 65 + c2 + 0] = v0.x; shA[r * 65 + c2 + 1] = v0.y;
        shA[r * 65 + c2 + 2] = v1.x; shA[r * 65 + c2 + 3] = v1.y;
        shA[r * 65 + c2 + 4] = v2.x; shA[r * 65 + c2 + 5] = v2.y;
        shA[r * 65 + c2 + 6] = v3.x; shA[r * 65 + c2 + 7] = v3.y;
      }
    }
    __syncthreads();

    // ---- phase B: TRSM trailing rows + z row ----
    {
      float dinv = 1.0f / shA[lane * 65 + lane];
      int gw = bx * 4 + wv;
      for (int ri = gw; ri < Rtot; ri += NBLK * 4) {
        int r = j0 + 64 + ri;
        float* grow = (r < Q) ? (G + (size_t)r * Q + j0) : (z + j0);
        float a = coh_load4(grow + lane);
        for (int p = 0; p < 64; ++p) {
          float xp = __shfl(a, p) * __shfl(dinv, p);
          if (lane > p) a -= xp * shA[lane * 65 + p];
        }
        coh_store4(grow + lane, a * dinv);
      }
    }
    gbar(arrive, release, ++ep);

    // ---- phase C: trailing SYRK + z update; block 0 preps next diag ----
    if (nb > 0) {
      int ntri = nb * (nb + 1) / 2;
      if (bx == 0) {
        int D0 = j0 + 64;
        syrk_tile(G, j0, D0, D0, shA, shB);   // update next diag tile
        asm volatile("s_waitcnt vmcnt(0)" ::: "memory");
        __syncthreads();
        if (wv == 0) {
          float rr[64];
          wave_chol64_coh(G + (size_t)D0 * Q + D0, rr);
          float dv = 1.0f;
#pragma unroll
          for (int k2 = 0; k2 < 32; ++k2) {
            coh_store8(ldstage + lane * 64 + k2 * 2, rr[k2 * 2], rr[k2 * 2 + 1]);
#pragma unroll
            for (int j = 0; j < 2; ++j)
              if (k2 * 2 + j == lane) dv = rr[k2 * 2 + j];
          }
          float lg = logf(dv);
#pragma unroll
          for (int o = 32; o > 0; o >>= 1) lg += __shfl_down(lg, o);
          if (lane == 0) atomicAdd(&scal[3], lg);
        }
      } else {
        int njobs = ntri + nb;
        for (int job = bx - 1; job < njobs; job += NBLK - 1) {
          __syncthreads();
          if (job < ntri) {
            if (job == 0) continue;   // diag tile: block 0's
            int bi = (int)((sqrtf(8.0f * (float)job + 1.0f) - 1.0f) * 0.5f);
            while ((bi + 1) * (bi + 2) / 2 <= job) ++bi;
            while (bi * (bi + 1) / 2 > job) --bi;
            int bk = job - bi * (bi + 1) / 2;
            syrk_tile(G, j0, j0 + 64 + bi * 64, j0 + 64 + bk * 64, shA, shB);
          } else {
            int bk = job - ntri;
            int C0 = j0 + 64 + bk * 64;
            if (tid < 64) z1s[tid] = coh_load4(z + j0 + tid);
            __syncthreads();
            int rw = tid >> 2, part = tid & 3;
            const float* Lr = G + (size_t)(C0 + rw) * Q + j0;
            float ssum = 0.f;
            for (int p = part; p < 64; p += 4) ssum += coh_load4(Lr + p) * z1s[p];
            ssum += __shfl_down(ssum, 2);
            ssum += __shfl_down(ssum, 1);
            if (part == 0) {
              float zc = coh_load4(z + C0 + rw);
              coh_store4(z + C0 + rw, zc - ssum);
            }
          }
        }
      }
    }
    gbar(arrive, release, ++ep);
  }

  // ---- final assembly (block 0) ----
  if (bx == 0) {
    float bv = 0.f;
    for (int i = tid; i < Q; i += 256) {
      float zi = coh_load4(z + i);
      bv += zi * zi;
    }
    float bvs = block_sum256(bv, red);
    if (tid == 0) {
      float s2e = s2e_p[0], s2b = s2b_p[0];
      float sig2 = s2e + s2b;
      float c = s2e / sig2;
      float slp = coh_load4(&scal[0]), mtm = coh_load4(&scal[1]);
      float tw = coh_load4(&scal[2]), sl = coh_load4(&scal[3]);
      float tty = (tw - bvs) / c;          // t' y
      float mrm = (mtm - tty) / c;         // m' R^{-1} m
      float logdetR = (float)(NOBS - Q) * logf(c) + 2.0f * sl;
      out[0] = 0.5f * logdetR + 0.5f * mrm - 0.5f * mtm + 0.5f * slp;
    }
  }
}

// ---------------------------------------------------------------------------
extern "C" void kernel_launch(void* const* d_in, const int* in_sizes, int n_in,
                              void* d_out, int out_size, void* d_ws, size_t ws_size,
                              hipStream_t stream) {
  const float* yt   = (const float*)d_in[0];
  const float* yp   = (const float*)d_in[1];
  const int*   zidx = (const int*)d_in[2];
  const float* dist = (const float*)d_in[3];
  const float* s2e  = (const float*)d_in[4];
  const float* s2b  = (const float*)d_in[5];
  const float* ell  = (const float*)d_in[6];

  float* ws   = (float*)d_ws;
  float* G    = ws;                         // Q*Q floats = 16 MB
  float* z    = ws + (size_t)Q * Q;         // Q
  float* t    = z + Q;                      // Q
  int*   cnt  = (int*)(t + Q);              // Q ints
  float* scal = t + 2 * Q;                  // 8: slp, mtm, tw, sumlogL
  unsigned* arrive  = (unsigned*)(scal + 8);   // 256
  unsigned* release = arrive + 256;            // 1 (+3 pad)
  float* ldstage = (float*)(release + 4);      // 64*64 staged diag factor

  // zero t, cnt, scal, barrier flags
  hipMemsetAsync(t, 0, (2 * Q + 8 + 260) * sizeof(float), stream);

  obs_kernel<<<NOBS / 256, 256, 0, stream>>>(yt, yp, zidx, s2e, s2b, t, cnt, scal);
  build_G<<<(Q * Q) / 256, 256, 0, stream>>>(dist, s2e, s2b, ell, cnt, G);
  matvec_kernel<<<Q, 256, 0, stream>>>(dist, s2e, s2b, ell, cnt, t, z, scal);

  // Plain launch (NOT cooperative): 256 blocks x 256 thr, 36KB LDS each ->
  // co-residency guaranteed by capacity; custom gbar handles grid sync.
  chol_coop<<<dim3(NBLK), dim3(256), 0, stream>>>(
      G, z, scal, arrive, release, ldstage, s2e, s2b, (float*)d_out);
}